// Round 4
// baseline (131.636 us; speedup 1.0000x reference)
//
#include <hip/hip_runtime.h>

// Problem constants
#define BB 256
#define NN 5
#define CHW 64000            // C*H*W floats per (b,n)
#define DD 800               // 32*5*5 pooled dims
#define EPSF 1e-8f
#define TPB 1024

typedef float f4 __attribute__((ext_vector_type(4)));

// Fused kernel, one b per block (grid = 256):
//  Phase A: pool x[b] -> feats LDS, walking each channel-group BACK-TO-FRONT
//           so the L3-resident set at end of A is the FRONT of every slab.
//  Phase B: all 16 waves compute cosine sims -> s_sim.
//  Phase C: out[b] = sum_n sim[n]*x[b,n], forward order, NONTEMPORAL loads
//           (hits serve from L3; misses don't evict other blocks' front data).
__global__ __launch_bounds__(TPB, 4) void k_fused(const float* __restrict__ x,
                                                  float* __restrict__ out) {
    __shared__ float feats[NN * DD];   // 16000 B
    __shared__ float red[17][11];      // 16 wave partials + 1 final row
    __shared__ float s_sim[NN];
    const int tid = threadIdx.x;
    const int b = blockIdx.x;
    const float* __restrict__ xb = x + (size_t)b * NN * CHW;

    // ---------------- Phase A: pool (reverse walk) ----------------
    if (tid < NN * 160) {
        const int n  = tid / 160;
        const int r  = tid - n * 160;
        const int oc = r / 5;
        const int oh = r - oc * 5;
        // channel c = oc*20+cc; rows h=2oh,2oh+1 are 20 contiguous floats.
        const f4* __restrict__ p = reinterpret_cast<const f4*>(xb) +
                                   (size_t)n * (CHW / 4) + oc * 500 + oh * 5;
        float s0 = 0.f, s1 = 0.f, s2 = 0.f, s3 = 0.f, s4 = 0.f;
        #pragma unroll 4
        for (int cc = 19; cc >= 0; --cc) {
            const f4 v0 = p[cc * 25 + 0];   // h0 w0..3
            const f4 v1 = p[cc * 25 + 1];   // h0 w4..7
            const f4 v2 = p[cc * 25 + 2];   // h0 w8,9 | h1 w0,1
            const f4 v3 = p[cc * 25 + 3];   // h1 w2..5
            const f4 v4 = p[cc * 25 + 4];   // h1 w6..9
            s0 += (v0.x + v0.y) + (v2.z + v2.w);
            s1 += (v0.z + v0.w) + (v3.x + v3.y);
            s2 += (v1.x + v1.y) + (v3.z + v3.w);
            s3 += (v1.z + v1.w) + (v4.x + v4.y);
            s4 += (v2.x + v2.y) + (v4.z + v4.w);
        }
        float* fp = feats + n * DD + oc * 25 + oh * 5;
        fp[0] = s0 * (1.f / 80.f);
        fp[1] = s1 * (1.f / 80.f);
        fp[2] = s2 * (1.f / 80.f);
        fp[3] = s3 * (1.f / 80.f);
        fp[4] = s4 * (1.f / 80.f);
    }
    __syncthreads();

    // ---------------- Phase B: sims, all waves ----------------
    float dot[NN] = {0.f, 0.f, 0.f, 0.f, 0.f};
    float na2[NN] = {0.f, 0.f, 0.f, 0.f, 0.f};
    float nb2 = 0.f;
    if (tid < DD) {
        float f[NN];
        float pr = 0.f;
        #pragma unroll
        for (int n = 0; n < NN; ++n) { f[n] = feats[n * DD + tid]; pr += f[n]; }
        #pragma unroll
        for (int n = 0; n < NN; ++n) { dot[n] = f[n] * pr; na2[n] = f[n] * f[n]; }
        nb2 = pr * pr;
    }
    #pragma unroll
    for (int off = 32; off >= 1; off >>= 1) {
        #pragma unroll
        for (int n = 0; n < NN; ++n) {
            dot[n] += __shfl_down(dot[n], off, 64);
            na2[n] += __shfl_down(na2[n], off, 64);
        }
        nb2 += __shfl_down(nb2, off, 64);
    }
    const int wv = tid >> 6;
    if ((tid & 63) == 0) {
        #pragma unroll
        for (int n = 0; n < NN; ++n) { red[wv][n] = dot[n]; red[wv][5 + n] = na2[n]; }
        red[wv][10] = nb2;
    }
    __syncthreads();
    if (tid < 11) {
        float s = 0.f;
        #pragma unroll
        for (int w = 0; w < 16; ++w) s += red[w][tid];
        red[16][tid] = s;
    }
    __syncthreads();
    if (tid == 0) {
        const float nb = sqrtf(red[16][10]);
        #pragma unroll
        for (int n = 0; n < NN; ++n) {
            const float denom = fmaxf(sqrtf(red[16][5 + n]) * nb, EPSF);
            s_sim[n] = red[16][n] / denom;
        }
    }
    __syncthreads();

    // ---------------- Phase C: weighted sum (forward, NT loads) -------
    const float w0 = s_sim[0];
    const float w1 = s_sim[1];
    const float w2 = s_sim[2];
    const float w3 = s_sim[3];
    const float w4 = s_sim[4];
    const f4* __restrict__ xp4 = reinterpret_cast<const f4*>(xb);
    f4* __restrict__ op4 = reinterpret_cast<f4*>(out + (size_t)b * CHW);
    #pragma unroll 2
    for (int i = tid; i < CHW / 4; i += TPB) {
        const f4 a0 = __builtin_nontemporal_load(xp4 + i);
        const f4 a1 = __builtin_nontemporal_load(xp4 + i + 1 * (CHW / 4));
        const f4 a2 = __builtin_nontemporal_load(xp4 + i + 2 * (CHW / 4));
        const f4 a3 = __builtin_nontemporal_load(xp4 + i + 3 * (CHW / 4));
        const f4 a4 = __builtin_nontemporal_load(xp4 + i + 4 * (CHW / 4));
        f4 o = w0 * a0 + w1 * a1 + w2 * a2 + w3 * a3 + w4 * a4;
        __builtin_nontemporal_store(o, op4 + i);
    }
}

extern "C" void kernel_launch(void* const* d_in, const int* in_sizes, int n_in,
                              void* d_out, int out_size, void* d_ws, size_t ws_size,
                              hipStream_t stream) {
    const float* x = (const float*)d_in[0];
    float* out = (float*)d_out;
    k_fused<<<BB, TPB, 0, stream>>>(x, out);
}

// Round 5
// 131.032 us; speedup vs baseline: 1.0046x; 1.0046x over previous
//
#include <hip/hip_runtime.h>

// Problem constants
#define BB 256
#define NN 5
#define CHW 64000            // C*H*W floats per (b,n)
#define DD 800               // 32*5*5 pooled dims
#define EPSF 1e-8f

typedef float f4 __attribute__((ext_vector_type(4)));

// ---------------- Kernel A: pool, one thread per (b,n,oc,oh) cell-row ----
// 256*5*32*5 = 204800 threads. Each reads rows 2oh,2oh+1 of its 20 channels
// (20 x 5 float4, stride 400 B) and writes 5 pooled floats.
__global__ __launch_bounds__(256) void k_pool(const float* __restrict__ x,
                                              float* __restrict__ feats) {
    const int g = blockIdx.x * 256 + threadIdx.x;   // 0..204799
    const int b = g / 800;
    const int r = g - b * 800;
    const int n = r / 160;
    const int q = r - n * 160;
    const int oc = q / 5;
    const int oh = q - oc * 5;
    const f4* __restrict__ p = reinterpret_cast<const f4*>(x) +
                               ((size_t)b * NN + n) * (CHW / 4) + oc * 500 + oh * 5;
    float s0 = 0.f, s1 = 0.f, s2 = 0.f, s3 = 0.f, s4 = 0.f;
    #pragma unroll 4
    for (int cc = 0; cc < 20; ++cc) {
        const f4 v0 = p[cc * 25 + 0];   // h0 w0..3
        const f4 v1 = p[cc * 25 + 1];   // h0 w4..7
        const f4 v2 = p[cc * 25 + 2];   // h0 w8,9 | h1 w0,1
        const f4 v3 = p[cc * 25 + 3];   // h1 w2..5
        const f4 v4 = p[cc * 25 + 4];   // h1 w6..9
        s0 += (v0.x + v0.y) + (v2.z + v2.w);
        s1 += (v0.z + v0.w) + (v3.x + v3.y);
        s2 += (v1.x + v1.y) + (v3.z + v3.w);
        s3 += (v1.z + v1.w) + (v4.x + v4.y);
        s4 += (v2.x + v2.y) + (v4.z + v4.w);
    }
    float* fp = feats + ((size_t)b * NN + n) * DD + oc * 25 + oh * 5;
    fp[0] = s0 * (1.f / 80.f);
    fp[1] = s1 * (1.f / 80.f);
    fp[2] = s2 * (1.f / 80.f);
    fp[3] = s3 * (1.f / 80.f);
    fp[4] = s4 * (1.f / 80.f);
}

// ---------------- Kernel B: cosine sims, one wave per b ----------------
__global__ __launch_bounds__(64) void k_sim(const float* __restrict__ feats,
                                            float* __restrict__ sim) {
    const int b = blockIdx.x;
    const int lane = threadIdx.x;
    const float* __restrict__ fb = feats + (size_t)b * NN * DD;
    float dot[NN] = {0.f, 0.f, 0.f, 0.f, 0.f};
    float na2[NN] = {0.f, 0.f, 0.f, 0.f, 0.f};
    float nb2 = 0.f;
    for (int d = lane; d < DD; d += 64) {
        float f[NN];
        float p = 0.f;
        #pragma unroll
        for (int n = 0; n < NN; ++n) { f[n] = fb[n * DD + d]; p += f[n]; }
        #pragma unroll
        for (int n = 0; n < NN; ++n) {
            dot[n] += f[n] * p;
            na2[n] += f[n] * f[n];
        }
        nb2 += p * p;
    }
    #pragma unroll
    for (int off = 32; off >= 1; off >>= 1) {
        #pragma unroll
        for (int n = 0; n < NN; ++n) {
            dot[n] += __shfl_down(dot[n], off, 64);
            na2[n] += __shfl_down(na2[n], off, 64);
        }
        nb2 += __shfl_down(nb2, off, 64);
    }
    if (lane == 0) {
        const float nb = sqrtf(nb2);
        #pragma unroll
        for (int n = 0; n < NN; ++n) {
            const float denom = fmaxf(sqrtf(na2[n]) * nb, EPSF);
            sim[b * NN + n] = dot[n] / denom;
        }
    }
}

// ---------------- Kernel C: out[b] = sum_n sim[b,n] * x[b,n] -----------
// One float4 per thread; NT loads (misses don't allocate -> preserve the
// L3 residency left by k_pool), NT stores (out is write-once).
__global__ __launch_bounds__(256) void k_out(const float* __restrict__ x,
                                             const float* __restrict__ sim,
                                             float* __restrict__ out) {
    const int i = blockIdx.x * 256 + threadIdx.x;   // 0 .. BB*16000-1
    const int b = i / 16000;                        // wave-uniform (16000%64==0)
    const int r = i - b * 16000;
    const f4* __restrict__ xp =
        reinterpret_cast<const f4*>(x) + (size_t)b * (NN * 16000) + r;
    const float s0 = sim[b * NN + 0];
    const float s1 = sim[b * NN + 1];
    const float s2 = sim[b * NN + 2];
    const float s3 = sim[b * NN + 3];
    const float s4 = sim[b * NN + 4];
    const f4 a0 = __builtin_nontemporal_load(xp + 0 * 16000);
    const f4 a1 = __builtin_nontemporal_load(xp + 1 * 16000);
    const f4 a2 = __builtin_nontemporal_load(xp + 2 * 16000);
    const f4 a3 = __builtin_nontemporal_load(xp + 3 * 16000);
    const f4 a4 = __builtin_nontemporal_load(xp + 4 * 16000);
    f4 o = s0 * a0 + s1 * a1 + s2 * a2 + s3 * a3 + s4 * a4;
    __builtin_nontemporal_store(o, reinterpret_cast<f4*>(out) + i);
}

extern "C" void kernel_launch(void* const* d_in, const int* in_sizes, int n_in,
                              void* d_out, int out_size, void* d_ws, size_t ws_size,
                              hipStream_t stream) {
    const float* x = (const float*)d_in[0];
    float* out = (float*)d_out;
    // workspace layout: feats [B*N*800] f32, then sim [B*N] f32
    float* feats = (float*)d_ws;
    float* sim = feats + (size_t)BB * NN * DD;

    k_pool<<<BB * NN * 160 / 256, 256, 0, stream>>>(x, feats);   // 800 blocks
    k_sim<<<BB, 64, 0, stream>>>(feats, sim);
    k_out<<<BB * 16000 / 256, 256, 0, stream>>>(x, sim, out);    // 16000 blocks
}